// Round 1
// baseline (149.914 us; speedup 1.0000x reference)
//
#include <hip/hip_runtime.h>
#include <math.h>

#define HH 480
#define WW 640
#define NL 100
#define NREF 20
#define TILES 16
#define ROWS_PER_TILE (HH / TILES) /* 30 */

// ws float layout:
//  [0..239]   tri data: k*12 + {ex,ey,vx,vy} x 3 edges
//  [240..339] accum:    k*5  + {cnt, sx, sy, sxx, syy}
//  [340..359] active flag per rank k (1.0 if k < top_num)
//  int at float-index 360: done counter

__global__ void plane_setup_kernel(const float* __restrict__ line_pred,
                                   const float* __restrict__ line_score,
                                   float* __restrict__ w) {
    __shared__ int s_flags[128];
    __shared__ int s_topnum;
    int i = threadIdx.x; // 0..127

    float s0 = 0.0f, s1 = 0.0f;
    if (i < NL) { s0 = line_score[2 * i]; s1 = line_score[2 * i + 1]; }

    int flag = 0;
    if (i < NL) {
        float p0 = 1.0f / (1.0f + expf(s1 - s0)); // softmax prob of class 0
        flag = (p0 > 0.6f) ? 1 : 0;
    }
    s_flags[i] = flag;

    // zero accumulators and done counter (ws is poisoned 0xAA every call)
    if (i < NREF * 5) w[240 + i] = 0.0f;
    if (i == 0) ((int*)w)[360] = 0;

    __syncthreads();
    if (i == 0) {
        int nk = 0;
        for (int j = 0; j < NL; j++) nk += s_flags[j];
        s_topnum = (nk < NREF) ? nk : NREF;
    }
    __syncthreads();

    if (i < NL) {
        // stable rank: exactly reproduces jax.lax.top_k ordering (desc, ties -> lower idx)
        int rank = 0;
        for (int j = 0; j < NL; j++) {
            float sj = line_score[2 * j];
            rank += ((sj > s0) || (sj == s0 && j < i)) ? 1 : 0;
        }
        if (rank < NREF) {
            float c[6];
            #pragma unroll
            for (int q = 0; q < 6; q++) c[q] = line_pred[6 * i + q];
            float vx[3], vy[3];
            #pragma unroll
            for (int v = 0; v < 3; v++) {
                float x = rintf(c[2 * v] * (float)WW);      // round half-even == jnp.round
                float y = rintf(c[2 * v + 1] * (float)HH);
                vx[v] = fminf(fmaxf(x, 0.0f), (float)(WW - 1));
                vy[v] = fminf(fmaxf(y, 0.0f), (float)(HH - 1));
            }
            float* td = w + rank * 12;
            #pragma unroll
            for (int e = 0; e < 3; e++) {
                int n = (e + 1) % 3;
                td[e * 4 + 0] = vx[n] - vx[e]; // ex
                td[e * 4 + 1] = vy[n] - vy[e]; // ey
                td[e * 4 + 2] = vx[e];
                td[e * 4 + 3] = vy[e];
            }
            w[340 + rank] = (rank < s_topnum) ? 1.0f : 0.0f;
        }
    }
}

__global__ __launch_bounds__(256) void plane_accum_kernel(
    const float* __restrict__ depth, const int* __restrict__ valid,
    float* __restrict__ w, float* __restrict__ out) {
    const int t = blockIdx.x / TILES;    // triangle 0..19
    const int tile = blockIdx.x % TILES; // row tile 0..15
    const int tid = threadIdx.x;

    const float* td = w + t * 12;
    const float ex0 = td[0], ey0 = td[1], vx0 = td[2],  vy0 = td[3];
    const float ex1 = td[4], ey1 = td[5], vx1 = td[6],  vy1 = td[7];
    const float ex2 = td[8], ey2 = td[9], vx2 = td[10], vy2 = td[11];

    float cnt = 0.0f, sx = 0.0f, sy = 0.0f, sxx = 0.0f, syy = 0.0f;

    const int r0 = tile * ROWS_PER_TILE;
    for (int r = r0; r < r0 + ROWS_PER_TILE; r++) {
        const float py = (float)r;
        const bool hm = (r > 0), hp = (r < HH - 1);
        const float* rowm = depth + (r - 1) * WW;
        const float* row0 = depth + r * WW;
        const float* rowp = depth + (r + 1) * WW;
        for (int x = tid; x < WW; x += 256) {
            const bool hl = (x > 0), hr = (x < WW - 1);
            float a00 = 0.f, a01 = 0.f, a02 = 0.f, a10 = 0.f, a12 = 0.f,
                  a20 = 0.f, a21 = 0.f, a22 = 0.f;
            if (hm) { a01 = rowm[x]; if (hl) a00 = rowm[x - 1]; if (hr) a02 = rowm[x + 1]; }
            if (hl) a10 = row0[x - 1];
            if (hr) a12 = row0[x + 1];
            if (hp) { a21 = rowp[x]; if (hl) a20 = rowp[x - 1]; if (hr) a22 = rowp[x + 1]; }
            // XLA conv = cross-correlation, zero pad
            const float gx = (a00 - a02) + 2.0f * (a10 - a12) + (a20 - a22);
            const float gy = (a00 + 2.0f * a01 + a02) - (a20 + 2.0f * a21 + a22);
            const float nx = -gx, ny = -gy;

            const float px = (float)x;
            // exact in fp32: all operands are integers < 2^24
            const float d0 = ex0 * (py - vy0) - ey0 * (px - vx0);
            const float d1 = ex1 * (py - vy1) - ey1 * (px - vx1);
            const float d2 = ex2 * (py - vy2) - ey2 * (px - vx2);
            const bool pos = (d0 >= 0.0f) & (d1 >= 0.0f) & (d2 >= 0.0f);
            const bool neg = (d0 <= 0.0f) & (d1 <= 0.0f) & (d2 <= 0.0f);
            const bool m = (pos | neg) & (valid[r * WW + x] != 0);
            if (m) {
                cnt += 1.0f;
                sx += nx; sy += ny;
                sxx += nx * nx; syy += ny * ny;
            }
        }
    }

    // wave (64-lane) shuffle reduction, then cross-wave via LDS
    float vals[5] = {cnt, sx, sy, sxx, syy};
    #pragma unroll
    for (int off = 32; off > 0; off >>= 1) {
        #pragma unroll
        for (int q = 0; q < 5; q++) vals[q] += __shfl_down(vals[q], off);
    }
    __shared__ float red[4][5];
    __shared__ int s_last;
    const int lane = tid & 63, wid = tid >> 6;
    if (lane == 0) {
        #pragma unroll
        for (int q = 0; q < 5; q++) red[wid][q] = vals[q];
    }
    __syncthreads();
    if (tid == 0) {
        float tot[5];
        #pragma unroll
        for (int q = 0; q < 5; q++)
            tot[q] = red[0][q] + red[1][q] + red[2][q] + red[3][q];
        float* acc = w + 240 + t * 5;
        #pragma unroll
        for (int q = 0; q < 5; q++) atomicAdd(&acc[q], tot[q]);
        __threadfence();
        int done = atomicAdd((int*)w + 360, 1);
        s_last = (done == (int)gridDim.x - 1) ? 1 : 0;
    }
    __syncthreads();

    if (s_last && tid == 0) {
        // last block: final reduction over 20 triangles
        float loss = 0.0f, ninc = 0.0f;
        for (int k = 0; k < NREF; k++) {
            float* acc = w + 240 + k * 5;
            // atomic reads: device-coherent point (cross-XCD safe)
            float c   = atomicAdd(&acc[0], 0.0f);
            float sxk = atomicAdd(&acc[1], 0.0f);
            float syk = atomicAdd(&acc[2], 0.0f);
            float sxxk = atomicAdd(&acc[3], 0.0f);
            float syyk = atomicAdd(&acc[4], 0.0f);
            float safe = fmaxf(c, 1.0f);
            float mx = sxk / safe, my = syk / safe;
            // == sum((nx-mx)^2)/safe expanded; exact 0 when c==0
            float varx = (sxxk - 2.0f * mx * sxk + c * mx * mx) / safe;
            float vary = (syyk - 2.0f * my * syk + c * my * my) / safe;
            float inc = (c >= 100.0f) ? w[340 + k] : 0.0f;
            loss += inc * (varx + vary);
            ninc += inc;
        }
        out[0] = loss / fmaxf(ninc, 1.0f);
    }
}

extern "C" void kernel_launch(void* const* d_in, const int* in_sizes, int n_in,
                              void* d_out, int out_size, void* d_ws, size_t ws_size,
                              hipStream_t stream) {
    const float* depth_pred = (const float*)d_in[0];
    // d_in[1] = depth_gt (unused by reference)
    const float* line_pred  = (const float*)d_in[2];
    const float* line_score = (const float*)d_in[3];
    const int*   valid_mask = (const int*)d_in[4];
    float* out = (float*)d_out;
    float* w = (float*)d_ws;

    plane_setup_kernel<<<1, 128, 0, stream>>>(line_pred, line_score, w);
    plane_accum_kernel<<<NREF * TILES, 256, 0, stream>>>(depth_pred, valid_mask, w, out);
}

// Round 2
// 132.806 us; speedup vs baseline: 1.1288x; 1.1288x over previous
//
#include <hip/hip_runtime.h>
#include <math.h>

#define HH 480
#define WW 640
#define NL 100
#define NREF 20
#define TILES 48
#define RPT (HH / TILES) /* 10 rows per tile */

// ws float layout:
//  [0..239]   tri data: k*12 + {ex,ey,vx,vy} x 3 edges
//  [240..339] accum:    k*5  + {cnt, sx, sy, sxx, syy}
//  [340..359] active flag per rank k (1.0 if k < top_num)
//  int at float-index 360: done counter

__global__ void plane_setup_kernel(const float* __restrict__ line_pred,
                                   const float* __restrict__ line_score,
                                   float* __restrict__ w) {
    __shared__ float s_sc[NL];    // score[:,0] staged once -> rank loop is LDS-only
    __shared__ int s_flags[NL];
    __shared__ int s_topnum;
    int i = threadIdx.x; // 0..127

    float s0 = 0.0f;
    if (i < NL) {
        s0 = line_score[2 * i];
        float s1 = line_score[2 * i + 1];
        s_sc[i] = s0;
        float p0 = 1.0f / (1.0f + expf(s1 - s0)); // softmax prob of class 0
        s_flags[i] = (p0 > 0.6f) ? 1 : 0;
    }

    // zero accumulators and done counter (ws is poisoned 0xAA every call)
    if (i < NREF * 5) w[240 + i] = 0.0f;
    if (i == 0) ((int*)w)[360] = 0;

    __syncthreads();
    if (i == 0) {
        int nk = 0;
        for (int j = 0; j < NL; j++) nk += s_flags[j];
        s_topnum = (nk < NREF) ? nk : NREF;
    }
    __syncthreads();

    if (i < NL) {
        // stable rank: exactly reproduces jax.lax.top_k ordering (desc, ties -> lower idx)
        int rank = 0;
        for (int j = 0; j < NL; j++) {
            float sj = s_sc[j];
            rank += ((sj > s0) || (sj == s0 && j < i)) ? 1 : 0;
        }
        if (rank < NREF) {
            float c[6];
            #pragma unroll
            for (int q = 0; q < 6; q++) c[q] = line_pred[6 * i + q];
            float vx[3], vy[3];
            #pragma unroll
            for (int v = 0; v < 3; v++) {
                float x = rintf(c[2 * v] * (float)WW);      // round half-even == jnp.round
                float y = rintf(c[2 * v + 1] * (float)HH);
                vx[v] = fminf(fmaxf(x, 0.0f), (float)(WW - 1));
                vy[v] = fminf(fmaxf(y, 0.0f), (float)(HH - 1));
            }
            float* td = w + rank * 12;
            #pragma unroll
            for (int e = 0; e < 3; e++) {
                int n = (e + 1) % 3;
                td[e * 4 + 0] = vx[n] - vx[e]; // ex
                td[e * 4 + 1] = vy[n] - vy[e]; // ey
                td[e * 4 + 2] = vx[e];
                td[e * 4 + 3] = vy[e];
            }
            w[340 + rank] = (rank < s_topnum) ? 1.0f : 0.0f;
        }
    }
}

__global__ __launch_bounds__(256) void plane_accum_kernel(
    const float* __restrict__ depth, const int* __restrict__ valid,
    float* __restrict__ w, float* __restrict__ out) {
    // LDS staging: depth rows [base-1 .. base+RPT] (12 rows), valid rows as uchar.
    __shared__ float ds[(RPT + 2) * WW];          // 30720 B
    __shared__ unsigned char vsh[RPT * WW];       // 6400 B
    __shared__ float red[4][5];
    __shared__ int s_last;

    const int t = blockIdx.x / TILES;    // triangle 0..19
    const int tile = blockIdx.x % TILES; // row tile 0..47
    const int tid = threadIdx.x;
    const int base = tile * RPT;

    // stage depth: 12 rows x 160 float4, zero-fill out-of-image rows
    for (int idx = tid; idx < (RPT + 2) * (WW / 4); idx += 256) {
        const int lr = idx / (WW / 4);
        const int c4 = idx - lr * (WW / 4);
        const int g = base - 1 + lr;
        float4 v = make_float4(0.f, 0.f, 0.f, 0.f);
        if ((unsigned)g < (unsigned)HH) v = ((const float4*)depth)[g * (WW / 4) + c4];
        ((float4*)ds)[idx] = v;
    }
    // stage valid: 10 rows, int4 -> uchar4
    for (int idx = tid; idx < RPT * (WW / 4); idx += 256) {
        int4 v = ((const int4*)valid)[base * (WW / 4) + idx];
        *((uchar4*)&vsh[idx * 4]) = make_uchar4(v.x != 0, v.y != 0, v.z != 0, v.w != 0);
    }

    const float* td = w + t * 12;
    const float ex0 = td[0], ey0 = td[1], vx0 = td[2],  vy0 = td[3];
    const float ex1 = td[4], ey1 = td[5], vx1 = td[6],  vy1 = td[7];
    const float ex2 = td[8], ey2 = td[9], vx2 = td[10], vy2 = td[11];

    __syncthreads();

    float cnt = 0.0f, sx = 0.0f, sy = 0.0f, sxx = 0.0f, syy = 0.0f;

    for (int lr = 0; lr < RPT; lr++) {
        const float py = (float)(base + lr);
        const float* rm = ds + lr * WW;        // global row r-1 (zero-filled at image edge)
        const float* rc = ds + (lr + 1) * WW;  // row r
        const float* rp = ds + (lr + 2) * WW;  // row r+1
        const unsigned char* vrow = vsh + lr * WW;
        #pragma unroll
        for (int k = 0; k < 3; k++) {
            const int x = tid + k * 256;
            if (x < WW) {
                const float lf = (x > 0) ? 1.0f : 0.0f;
                const float rf = (x < WW - 1) ? 1.0f : 0.0f;
                const int xm = x - (x > 0);
                const int xp = x + (x < WW - 1);
                const float a00 = rm[xm] * lf, a01 = rm[x], a02 = rm[xp] * rf;
                const float a10 = rc[xm] * lf,               a12 = rc[xp] * rf;
                const float a20 = rp[xm] * lf, a21 = rp[x], a22 = rp[xp] * rf;
                // XLA conv = cross-correlation, zero pad
                const float gx = (a00 - a02) + 2.0f * (a10 - a12) + (a20 - a22);
                const float gy = (a00 + 2.0f * a01 + a02) - (a20 + 2.0f * a21 + a22);
                const float nx = -gx, ny = -gy;

                const float px = (float)x;
                // exact in fp32: all operands are integers < 2^24
                const float d0 = ex0 * (py - vy0) - ey0 * (px - vx0);
                const float d1 = ex1 * (py - vy1) - ey1 * (px - vx1);
                const float d2 = ex2 * (py - vy2) - ey2 * (px - vx2);
                const bool pos = (d0 >= 0.0f) & (d1 >= 0.0f) & (d2 >= 0.0f);
                const bool neg = (d0 <= 0.0f) & (d1 <= 0.0f) & (d2 <= 0.0f);
                const bool m = (pos | neg) & (vrow[x] != 0);
                if (m) {
                    cnt += 1.0f;
                    sx += nx; sy += ny;
                    sxx += nx * nx; syy += ny * ny;
                }
            }
        }
    }

    // wave (64-lane) shuffle reduction, then cross-wave via LDS
    float vals[5] = {cnt, sx, sy, sxx, syy};
    #pragma unroll
    for (int off = 32; off > 0; off >>= 1) {
        #pragma unroll
        for (int q = 0; q < 5; q++) vals[q] += __shfl_down(vals[q], off);
    }
    const int lane = tid & 63, wid = tid >> 6;
    if (lane == 0) {
        #pragma unroll
        for (int q = 0; q < 5; q++) red[wid][q] = vals[q];
    }
    __syncthreads();
    if (tid == 0) {
        float tot[5];
        #pragma unroll
        for (int q = 0; q < 5; q++)
            tot[q] = red[0][q] + red[1][q] + red[2][q] + red[3][q];
        float* acc = w + 240 + t * 5;
        #pragma unroll
        for (int q = 0; q < 5; q++) atomicAdd(&acc[q], tot[q]);
        __threadfence();
        int done = atomicAdd((int*)w + 360, 1);
        s_last = (done == (int)gridDim.x - 1) ? 1 : 0;
    }
    __syncthreads();

    if (s_last && tid == 0) {
        // last block: final reduction over 20 triangles
        float loss = 0.0f, ninc = 0.0f;
        for (int k = 0; k < NREF; k++) {
            float* acc = w + 240 + k * 5;
            // atomic reads: device-coherent point (cross-XCD safe)
            float c    = atomicAdd(&acc[0], 0.0f);
            float sxk  = atomicAdd(&acc[1], 0.0f);
            float syk  = atomicAdd(&acc[2], 0.0f);
            float sxxk = atomicAdd(&acc[3], 0.0f);
            float syyk = atomicAdd(&acc[4], 0.0f);
            float safe = fmaxf(c, 1.0f);
            float mx = sxk / safe, my = syk / safe;
            // == sum((nx-mx)^2)/safe expanded; exact 0 when c==0
            float varx = (sxxk - 2.0f * mx * sxk + c * mx * mx) / safe;
            float vary = (syyk - 2.0f * my * syk + c * my * my) / safe;
            float inc = (c >= 100.0f) ? w[340 + k] : 0.0f;
            loss += inc * (varx + vary);
            ninc += inc;
        }
        out[0] = loss / fmaxf(ninc, 1.0f);
    }
}

extern "C" void kernel_launch(void* const* d_in, const int* in_sizes, int n_in,
                              void* d_out, int out_size, void* d_ws, size_t ws_size,
                              hipStream_t stream) {
    const float* depth_pred = (const float*)d_in[0];
    // d_in[1] = depth_gt (unused by reference)
    const float* line_pred  = (const float*)d_in[2];
    const float* line_score = (const float*)d_in[3];
    const int*   valid_mask = (const int*)d_in[4];
    float* out = (float*)d_out;
    float* w = (float*)d_ws;

    plane_setup_kernel<<<1, 128, 0, stream>>>(line_pred, line_score, w);
    plane_accum_kernel<<<NREF * TILES, 256, 0, stream>>>(depth_pred, valid_mask, w, out);
}

// Round 3
// 102.828 us; speedup vs baseline: 1.4579x; 1.2915x over previous
//
#include <hip/hip_runtime.h>
#include <math.h>

#define HH 480
#define WW 640
#define NL 100
#define NREF 20
#define TILES 48
#define RPT (HH / TILES) /* 10 rows per tile */
#define GRID (NREF * TILES)

// ws layout: float w[0..99] = acc[t][5] {cnt,sx,sy,sxx,syy}; int at word 100 = done counter.
// Host zeroes the first 512 B via hipMemsetAsync each call (ws is re-poisoned to 0xAA).

__global__ __launch_bounds__(256) void plane_fused_kernel(
    const float* __restrict__ depth, const int* __restrict__ valid,
    const float* __restrict__ line_pred, const float* __restrict__ line_score,
    float* __restrict__ w, float* __restrict__ out) {

    __shared__ float ds[(RPT + 2) * WW];      // 30720 B: rows base-1 .. base+RPT
    __shared__ unsigned char vsh[RPT * WW];   // 6400 B
    __shared__ float s_sc[NL];
    __shared__ float red[4][5];
    __shared__ float sred[NREF * 5];
    __shared__ int s_sel, s_topnum, s_last;

    const int t = blockIdx.x / TILES;    // triangle rank 0..19
    const int tile = blockIdx.x % TILES; // row tile 0..47
    const int tid = threadIdx.x;
    const int base = tile * RPT;

    // ---- per-block triangle setup (identical across tiles; ~1 us, overlapped) ----
    float p0 = 0.0f, myscore = 0.0f;
    if (tid == 0) s_topnum = 0;
    if (tid < NL) {
        float2 sc = ((const float2*)line_score)[tid];
        myscore = sc.x;
        s_sc[tid] = sc.x;
        p0 = 1.0f / (1.0f + expf(sc.y - sc.x)); // softmax prob of class 0
    }

    // ---- stage depth: 12 rows x 160 float4, zero-fill out-of-image rows ----
    for (int idx = tid; idx < (RPT + 2) * (WW / 4); idx += 256) {
        const int lr = idx / (WW / 4);
        const int c4 = idx - lr * (WW / 4);
        const int g = base - 1 + lr;
        float4 v = make_float4(0.f, 0.f, 0.f, 0.f);
        if ((unsigned)g < (unsigned)HH) v = ((const float4*)depth)[g * (WW / 4) + c4];
        ((float4*)ds)[idx] = v;
    }
    // ---- stage valid: int4 -> uchar4 ----
    for (int idx = tid; idx < RPT * (WW / 4); idx += 256) {
        int4 v = ((const int4*)valid)[base * (WW / 4) + idx];
        *((uchar4*)&vsh[idx * 4]) = make_uchar4(v.x != 0, v.y != 0, v.z != 0, v.w != 0);
    }

    __syncthreads();

    if (tid < NL) {
        if (p0 > 0.6f) atomicAdd(&s_topnum, 1);
        // stable rank == jax.lax.top_k order (desc, ties -> lower idx); ranks are a permutation
        int rank = 0;
        for (int j = 0; j < NL; j++) {
            float sj = s_sc[j];
            rank += ((sj > myscore) || (sj == myscore && j < tid)) ? 1 : 0;
        }
        if (rank == t) s_sel = tid;
    }
    __syncthreads();

    const int sel = s_sel; // uniform -> scalar loads below
    float vxa[3], vya[3];
    #pragma unroll
    for (int v = 0; v < 3; v++) {
        float xx = rintf(line_pred[6 * sel + 2 * v] * (float)WW);     // round half-even
        float yy = rintf(line_pred[6 * sel + 2 * v + 1] * (float)HH);
        vxa[v] = fminf(fmaxf(xx, 0.f), (float)(WW - 1));
        vya[v] = fminf(fmaxf(yy, 0.f), (float)(HH - 1));
    }
    const float ex0 = vxa[1] - vxa[0], ey0 = vya[1] - vya[0], vx0 = vxa[0], vy0 = vya[0];
    const float ex1 = vxa[2] - vxa[1], ey1 = vya[2] - vya[1], vx1 = vxa[1], vy1 = vya[1];
    const float ex2 = vxa[0] - vxa[2], ey2 = vya[0] - vya[2], vx2 = vxa[2], vy2 = vya[2];

    // ---- main loop: 3-row register window, ~3 LDS reads/pixel ----
    float cnt = 0.f, sx = 0.f, sy = 0.f, sxx = 0.f, syy = 0.f;
    #pragma unroll
    for (int k = 0; k < 3; k++) {
        const int x = tid + (k << 8);
        if (x < WW) {
            const float fl = (x > 0) ? 1.f : 0.f;
            const float fr = (x < WW - 1) ? 1.f : 0.f;
            const int xm = x - (x > 0), xp = x + (x < WW - 1);
            const float px = (float)x;
            // per-strip constants of the edge functions
            const float h0 = ey0 * (px - vx0);
            const float h1 = ey1 * (px - vx1);
            const float h2 = ey2 * (px - vx2);
            float l0 = ds[xm] * fl,      c0 = ds[x],      r0 = ds[xp] * fr;
            float l1 = ds[WW + xm] * fl, c1 = ds[WW + x], r1 = ds[WW + xp] * fr;
            for (int lr = 0; lr < RPT; lr++) {
                const float* rw = ds + (lr + 2) * WW;
                const float l2 = rw[xm] * fl, c2 = rw[x], r2 = rw[xp] * fr;
                // XLA conv = cross-correlation, zero pad
                const float gx = (l0 - r0) + 2.f * (l1 - r1) + (l2 - r2);
                const float gy = (l0 + 2.f * c0 + r0) - (l2 + 2.f * c2 + r2);
                const float nx = -gx, ny = -gy;
                const float py = (float)(base + lr);
                // exact in fp32: integer operands, |products| < 2^24
                const float d0 = ex0 * (py - vy0) - h0;
                const float d1 = ex1 * (py - vy1) - h1;
                const float d2 = ex2 * (py - vy2) - h2;
                const bool pos = (d0 >= 0.f) & (d1 >= 0.f) & (d2 >= 0.f);
                const bool neg = (d0 <= 0.f) & (d1 <= 0.f) & (d2 <= 0.f);
                const bool m = (pos | neg) & (vsh[lr * WW + x] != 0);
                if (m) {
                    cnt += 1.f; sx += nx; sy += ny;
                    sxx += nx * nx; syy += ny * ny;
                }
                l0 = l1; c0 = c1; r0 = r1;
                l1 = l2; c1 = c2; r1 = r2;
            }
        }
    }

    // ---- block reduction ----
    float vals[5] = {cnt, sx, sy, sxx, syy};
    #pragma unroll
    for (int off = 32; off > 0; off >>= 1) {
        #pragma unroll
        for (int q = 0; q < 5; q++) vals[q] += __shfl_down(vals[q], off);
    }
    const int lane = tid & 63, wid = tid >> 6;
    if (lane == 0) {
        #pragma unroll
        for (int q = 0; q < 5; q++) red[wid][q] = vals[q];
    }
    __syncthreads();
    if (tid == 0) {
        float* acc = w + t * 5;
        #pragma unroll
        for (int q = 0; q < 5; q++)
            atomicAdd(&acc[q], red[0][q] + red[1][q] + red[2][q] + red[3][q]);
        __threadfence();
        int done = atomicAdd((int*)w + 100, 1);
        s_last = (done == GRID - 1) ? 1 : 0;
    }
    __syncthreads();

    // ---- last block: parallel final reduction (1 atomic round-trip, not 100 serial) ----
    if (s_last) {
        if (tid < NREF * 5) sred[tid] = atomicAdd(&w[tid], 0.0f); // coherent parallel reads
        __syncthreads();
        float val = 0.f, inc = 0.f;
        if (tid < NREF) {
            const float c    = sred[tid * 5 + 0];
            const float sxk  = sred[tid * 5 + 1];
            const float syk  = sred[tid * 5 + 2];
            const float sxxk = sred[tid * 5 + 3];
            const float syyk = sred[tid * 5 + 4];
            const float safe = fmaxf(c, 1.f);
            const float mx = sxk / safe, my = syk / safe;
            // == sum((nx-mx)^2)/safe expanded; exact 0 when c==0
            const float varx = (sxxk - 2.f * mx * sxk + c * mx * mx) / safe;
            const float vary = (syyk - 2.f * my * syk + c * my * my) / safe;
            inc = ((c >= 100.f) && (tid < s_topnum)) ? 1.f : 0.f;
            val = inc * (varx + vary);
        }
        if (tid < 64) { // lanes 20..63 carry zeros
            #pragma unroll
            for (int off = 32; off > 0; off >>= 1) {
                val += __shfl_down(val, off);
                inc += __shfl_down(inc, off);
            }
            if (tid == 0) out[0] = val / fmaxf(inc, 1.f);
        }
    }
}

extern "C" void kernel_launch(void* const* d_in, const int* in_sizes, int n_in,
                              void* d_out, int out_size, void* d_ws, size_t ws_size,
                              hipStream_t stream) {
    const float* depth_pred = (const float*)d_in[0];
    // d_in[1] = depth_gt (unused by reference)
    const float* line_pred  = (const float*)d_in[2];
    const float* line_score = (const float*)d_in[3];
    const int*   valid_mask = (const int*)d_in[4];
    float* out = (float*)d_out;
    float* w = (float*)d_ws;

    hipMemsetAsync(w, 0, 512, stream); // zero acc[100] + done counter (graph-capturable)
    plane_fused_kernel<<<GRID, 256, 0, stream>>>(depth_pred, valid_mask,
                                                 line_pred, line_score, w, out);
}